// Round 10
// baseline (1989.028 us; speedup 1.0000x reference)
//
#include <hip/hip_runtime.h>
#include <hip/hip_bf16.h>

typedef unsigned short u16;
typedef short s16x8 __attribute__((ext_vector_type(8)));
typedef u16 u16x8 __attribute__((ext_vector_type(8)));
typedef float f32x4 __attribute__((ext_vector_type(4)));

// buckets: partition/sort granularity = 256 dst; agg tile = 64 dst; src-deg buckets = 1024
#define DBK 256
#define TILE 64

__device__ __forceinline__ u16 f2bf(float f) {
    __hip_bfloat16 b = __float2bfloat16(f);
    return __builtin_bit_cast(u16, b);
}
__device__ __forceinline__ float bf2f(u16 u) {
    unsigned int x = ((unsigned int)u) << 16;
    return __builtin_bit_cast(float, x);
}

// ---------------- histogram over dst-buckets (256) and src-buckets (1024) ----------------

__global__ __launch_bounds__(256) void bhist_k(const int* __restrict__ src,
                                               const int* __restrict__ dst,
                                               int* __restrict__ bcntT,  // [NBK] dst/256
                                               int* __restrict__ bcntS,  // [NSB] src/1024
                                               int E, int chunk, int NBK, int NSB) {
    __shared__ int hT[400], hS[128];
    const int base = blockIdx.x * chunk;
    const int end = (base + chunk) < E ? (base + chunk) : E;
    for (int i = threadIdx.x; i < NBK; i += 256) hT[i] = 0;
    for (int i = threadIdx.x; i < NSB; i += 256) hS[i] = 0;
    __syncthreads();
    for (int i = base + threadIdx.x; i < end; i += 256) {
        atomicAdd(&hT[dst[i] >> 8], 1);
        atomicAdd(&hS[src[i] >> 10], 1);
    }
    __syncthreads();
    for (int i = threadIdx.x; i < NBK; i += 256)
        if (hT[i]) atomicAdd(&bcntT[i], hT[i]);
    for (int i = threadIdx.x; i < NSB; i += 256)
        if (hS[i]) atomicAdd(&bcntS[i], hS[i]);
}

// single block: exclusive-scan both bucket arrays -> bases + cursors
__global__ void bscan_k(const int* __restrict__ bcntT, const int* __restrict__ bcntS,
                        int* __restrict__ tbaseB, int* __restrict__ tcurB,
                        int* __restrict__ sbase, int* __restrict__ scur,
                        int* __restrict__ tstart, int NBK, int NSB, int NT, int E) {
    __shared__ int part[256];
    __shared__ int arr2[128];
    const int t = threadIdx.x;
    // dst buckets (NBK <= 512): 2 per thread
    const int i0 = t * 2, i1 = t * 2 + 1;
    int v0 = (i0 < NBK) ? bcntT[i0] : 0;
    int v1 = (i1 < NBK) ? bcntT[i1] : 0;
    part[t] = v0 + v1;
    __syncthreads();
    for (int d = 1; d < 256; d <<= 1) {
        int add = (t >= d) ? part[t - d] : 0;
        __syncthreads();
        part[t] += add;
        __syncthreads();
    }
    int excl = part[t] - (v0 + v1);
    if (i0 < NBK) { tbaseB[i0] = excl; tcurB[i0] = excl; }
    if (i1 < NBK) { tbaseB[i1] = excl + v0; tcurB[i1] = excl + v0; }
    if (t == 0) { tbaseB[NBK] = E; tstart[NT] = E; }
    // src buckets (NSB <= 128)
    int vs = (t < NSB) ? bcntS[t] : 0;
    if (t < 128) arr2[t] = vs;
    __syncthreads();
    for (int d = 1; d < 128; d <<= 1) {
        int add = (t >= d && t < 128) ? arr2[t - d] : 0;
        __syncthreads();
        if (t < 128) arr2[t] += add;
        __syncthreads();
    }
    if (t < NSB) { int e2 = arr2[t] - vs; sbase[t] = e2; scur[t] = e2; }
    if (t == 0) sbase[NSB] = E;
}

// partition: scatter packed keys by dst-bucket, src values by src-bucket
// key = (tile_local<<23) | (src<<6) | dst_local  (2+17+6 = 25 bits)
__global__ __launch_bounds__(256) void part_k(const int* __restrict__ src,
                                              const int* __restrict__ dst,
                                              int* __restrict__ tcurB,
                                              int* __restrict__ scur,
                                              int* __restrict__ ekey,
                                              int* __restrict__ sb,
                                              int E, int chunk, int NBK, int NSB) {
    __shared__ int hT[400], hS[128];
    const int base = blockIdx.x * chunk;
    const int end = (base + chunk) < E ? (base + chunk) : E;
    for (int i = threadIdx.x; i < NBK; i += 256) hT[i] = 0;
    for (int i = threadIdx.x; i < NSB; i += 256) hS[i] = 0;
    __syncthreads();
    for (int i = base + threadIdx.x; i < end; i += 256) {
        atomicAdd(&hT[dst[i] >> 8], 1);
        atomicAdd(&hS[src[i] >> 10], 1);
    }
    __syncthreads();
    for (int i = threadIdx.x; i < NBK; i += 256) {
        int c = hT[i];
        hT[i] = c ? atomicAdd(&tcurB[i], c) : 0;
    }
    for (int i = threadIdx.x; i < NSB; i += 256) {
        int c = hS[i];
        hS[i] = c ? atomicAdd(&scur[i], c) : 0;
    }
    __syncthreads();
    for (int i = base + threadIdx.x; i < end; i += 256) {
        int d = dst[i], s = src[i];
        int pos = atomicAdd(&hT[d >> 8], 1);
        ekey[pos] = (((d & 255) >> 6) << 23) | (s << 6) | (d & 63);
        int pos2 = atomicAdd(&hS[s >> 10], 1);
        sb[pos2] = s;
    }
}

// per dst-bucket: bitonic-sort the packed keys (canonical order => determinism),
// then dl-histogram -> deg_in + per-tile start offsets.
__global__ __launch_bounds__(256) void tilesort_k(int* __restrict__ ekey,
                                                  const int* __restrict__ tbaseB,
                                                  int* __restrict__ tstart,
                                                  int* __restrict__ din,
                                                  int NT, int N) {
    __shared__ int keys[16384];  // 64KB
    __shared__ int h64[256];
    __shared__ int tc[4];
    const int b = blockIdx.x, tid = threadIdx.x;
    const int beg = tbaseB[b], end = tbaseB[b + 1];
    const int L = end - beg;
    if (L > 0 && L <= 16384) {
        int P = 1024;
        while (P < L) P <<= 1;
        for (int i = tid; i < P; i += 256) keys[i] = (i < L) ? ekey[beg + i] : 0x7fffffff;
        __syncthreads();
        for (int k = 2; k <= P; k <<= 1) {
            for (int j = k >> 1; j > 0; j >>= 1) {
                for (int i = tid; i < P; i += 256) {
                    int ix = i ^ j;
                    if (ix > i) {
                        int a = keys[i], c = keys[ix];
                        bool asc = ((i & k) == 0);
                        if (asc ? (a > c) : (a < c)) { keys[i] = c; keys[ix] = a; }
                    }
                }
                __syncthreads();
            }
        }
        for (int i = tid; i < L; i += 256) ekey[beg + i] = keys[i];
    } else if (L > 16384 && tid == 0) {
        // fallback (unreachable for this edge distribution) — keeps correctness
        for (int i = beg + 1; i < end; i++) {
            int v = ekey[i], j = i - 1;
            while (j >= beg && ekey[j] > v) { ekey[j + 1] = ekey[j]; j--; }
            ekey[j + 1] = v;
        }
    }
    if (tid < 4) tc[tid] = 0;
    h64[tid] = 0;
    __syncthreads();
    for (int i = tid; i < L; i += 256) {
        int k = ekey[beg + i];
        atomicAdd(&h64[((k >> 23) & 3) * 64 + (k & 63)], 1);
    }
    __syncthreads();
    {
        int node = b * DBK + tid;
        if (node < N) din[node] = h64[tid];
    }
    if (tid < 4) {
        int s = 0;
#pragma unroll
        for (int x = 0; x < 64; x++) s += h64[tid * 64 + x];
        tc[tid] = s;
    }
    __syncthreads();
    if (tid < 4) {
        int p = beg;
        for (int x = 0; x < tid; x++) p += tc[x];
        int ti = b * 4 + tid;
        if (ti <= NT) tstart[ti] = p;
    }
}

// per src-bucket: LDS histogram -> deg_out (dense)
__global__ __launch_bounds__(256) void bdeg_k(const int* __restrict__ sb,
                                              const int* __restrict__ sbase,
                                              int* __restrict__ dout, int N) {
    __shared__ int hist[1024];
    const int b = blockIdx.x;
    const int beg = sbase[b], end = sbase[b + 1];
    const int nbase = b << 10;
    const int nlen = (N - nbase) < 1024 ? (N - nbase) : 1024;
    for (int i = threadIdx.x; i < 1024; i += 256) hist[i] = 0;
    __syncthreads();
    for (int i = beg + threadIdx.x; i < end; i += 256)
        atomicAdd(&hist[sb[i] - nbase], 1);
    __syncthreads();
    for (int i = threadIdx.x; i < nlen; i += 256) dout[nbase + i] = hist[i];
}

__global__ void norms_k(const int* __restrict__ dout, const int* __restrict__ din,
                        float* __restrict__ ns, float* __restrict__ nd, int n) {
    int i = blockIdx.x * blockDim.x + threadIdx.x;
    if (i < n) {
        ns[i] = 1.0f / sqrtf(fmaxf((float)dout[i], 1.0f));
        nd[i] = 1.0f / sqrtf(fmaxf((float)din[i], 1.0f));
    }
}

// transpose-convert W[k][n] (f32) -> Wt[n][k] (bf16)
__global__ void convt_k(const float* __restrict__ W, u16* __restrict__ Wt, int K, int Nn) {
    int i = blockIdx.x * blockDim.x + threadIdx.x;
    if (i < K * Nn) {
        int n = i / K, k = i - n * K;
        Wt[i] = f2bf(W[(size_t)k * Nn + n]);
    }
}

// ---------------- GEMM: C[M][256] = A(scaled,bf16) @ W, tile 128x256x64, 8 waves ----------------

template <int K, bool AF32>
__global__ __launch_bounds__(512) void gemm_k(const void* __restrict__ Ap,
                                              const float* __restrict__ nsrc,
                                              const u16* __restrict__ Bt,  // [256][K] bf16 (W^T)
                                              u16* __restrict__ C, int M) {
    constexpr int BKt = 64;
    __shared__ u16 Al[128 * BKt];
    __shared__ u16 Bl[256 * BKt];
    const int tid = threadIdx.x, lane = tid & 63, wid = tid >> 6;
    const int wr = wid >> 2, wc = wid & 3;
    const int l15 = lane & 15, lhi = lane >> 4;
    const int bm = blockIdx.x * 128;
    f32x4 acc[4][4] = {};

    for (int k0 = 0; k0 < K; k0 += BKt) {
#pragma unroll
        for (int i = 0; i < 2; i++) {
            int G = i * 512 + tid, row = G >> 3, gk = G & 7;
            int grow = bm + row;
            grow = grow < M ? grow : M - 1;
            u16x8 w;
            if constexpr (AF32) {
                const float* A = (const float*)Ap;
                const f32x4 v0 = *(const f32x4*)(A + (size_t)grow * K + k0 + gk * 8);
                const f32x4 v1 = *(const f32x4*)(A + (size_t)grow * K + k0 + gk * 8 + 4);
                const float ns = nsrc[grow];
                w[0] = f2bf(v0[0] * ns); w[1] = f2bf(v0[1] * ns);
                w[2] = f2bf(v0[2] * ns); w[3] = f2bf(v0[3] * ns);
                w[4] = f2bf(v1[0] * ns); w[5] = f2bf(v1[1] * ns);
                w[6] = f2bf(v1[2] * ns); w[7] = f2bf(v1[3] * ns);
            } else {
                const u16* A = (const u16*)Ap;
                w = *(const u16x8*)(A + (size_t)grow * K + k0 + gk * 8);
            }
            int idx = (row * BKt + gk * 8) ^ ((row & 7) << 3);
            *(u16x8*)(Al + idx) = w;
        }
#pragma unroll
        for (int i = 0; i < 4; i++) {
            int G = i * 512 + tid, row = G >> 3, gk = G & 7;
            u16x8 wb = *(const u16x8*)(Bt + (size_t)row * K + k0 + gk * 8);
            int idx = (row * BKt + gk * 8) ^ ((row & 7) << 3);
            *(u16x8*)(Bl + idx) = wb;
        }
        __syncthreads();

        s16x8 af[2][4], bfr[2][4];
#pragma unroll
        for (int kk = 0; kk < 2; kk++) {
#pragma unroll
            for (int mi = 0; mi < 4; mi++) {
                int row = wr * 64 + mi * 16 + l15;
                int idx = (row * BKt + kk * 32 + lhi * 8) ^ ((row & 7) << 3);
                af[kk][mi] = *(const s16x8*)(Al + idx);
            }
#pragma unroll
            for (int ni = 0; ni < 4; ni++) {
                int n = wc * 64 + ni * 16 + l15;
                int idx = (n * BKt + kk * 32 + lhi * 8) ^ ((n & 7) << 3);
                bfr[kk][ni] = *(const s16x8*)(Bl + idx);
            }
        }
#pragma unroll
        for (int kk = 0; kk < 2; kk++)
#pragma unroll
            for (int mi = 0; mi < 4; mi++)
#pragma unroll
                for (int ni = 0; ni < 4; ni++)
                    acc[mi][ni] = __builtin_amdgcn_mfma_f32_16x16x32_bf16(
                        af[kk][mi], bfr[kk][ni], acc[mi][ni], 0, 0, 0);
        __syncthreads();
    }

#pragma unroll
    for (int mi = 0; mi < 4; mi++) {
#pragma unroll
        for (int r = 0; r < 4; r++) {
            int grow = bm + wr * 64 + mi * 16 + lhi * 4 + r;
            if (grow < M) {
#pragma unroll
                for (int ni = 0; ni < 4; ni++) {
                    int gcol = wc * 64 + ni * 16 + l15;
                    C[(size_t)grow * 256 + gcol] = f2bf(acc[mi][ni][r]);
                }
            }
        }
    }
}

// ---------------- aggregation: cache-blocked src-sorted sweep ----------------
// Block = 64-dst tile; acc[64][256] f32 in LDS; thread = channel (tid=c).
// Edges sorted by src (canonical) => concurrent blocks sweep src space in phase
// => h rows served from L2/L3 instead of repeated HBM fetch. Deterministic:
// fixed edge order, per-(dl,c) f32 adds sequential per thread.

__global__ __launch_bounds__(256) void agg2_k(const u16* __restrict__ h,
                                              const int* __restrict__ ekey,
                                              const int* __restrict__ tstart,
                                              const float* __restrict__ nd,
                                              const float* __restrict__ bias,
                                              const float* __restrict__ alpha,
                                              const float* __restrict__ ns,
                                              u16* __restrict__ obf, float* __restrict__ of,
                                              int n) {
    __shared__ float acc[TILE * 256];  // 64KB
    __shared__ int kb[1024];           // 4KB key staging
    const int t = blockIdx.x, tid = threadIdx.x;
    const int beg = tstart[t], end = tstart[t + 1];
    for (int i = tid; i < TILE * 256; i += 256) acc[i] = 0.f;
    const float bv = bias[tid], av = alpha[tid];
    __syncthreads();

    int dA[8], dB[8];
    float xA[8], xB[8];
    auto loadB = [&](int base, int* dd, float* xx) {
#pragma unroll
        for (int u = 0; u < 8; u++) {
            int k = kb[base + u];
            dd[u] = (k & 63) << 8;
            xx[u] = bf2f(h[(size_t)((k >> 6) & 0x1FFFF) * 256 + tid]);
        }
    };
    auto accB = [&](int* dd, float* xx) {
#pragma unroll
        for (int u = 0; u < 8; u++) acc[dd[u] + tid] += xx[u];
    };

    for (int ch = beg; ch < end; ch += 1024) {
        const int m = (end - ch) < 1024 ? (end - ch) : 1024;
        for (int i = tid; i < m; i += 256) kb[i] = ekey[ch + i];
        __syncthreads();
        int e = 0;
        if (m >= 16) {
            loadB(0, dA, xA);
            e = 8;
            for (; e + 15 < m; e += 16) {
                loadB(e, dB, xB);
                accB(dA, xA);
                loadB(e + 8, dA, xA);
                accB(dB, xB);
            }
            if (e + 7 < m) {
                loadB(e, dB, xB);
                accB(dA, xA);
                accB(dB, xB);
                e += 8;
            } else {
                accB(dA, xA);
            }
        }
        for (; e < m; ++e) {
            int k = kb[e];
            acc[((k & 63) << 8) + tid] += bf2f(h[(size_t)((k >> 6) & 0x1FFFF) * 256 + tid]);
        }
        __syncthreads();
    }

    // epilogue: norm_dst, bias, PReLU, [x norm_src -> bf16]
    for (int dl = 0; dl < TILE; ++dl) {
        int node = t * TILE + dl;
        if (node >= n) break;
        float v = acc[dl * 256 + tid] * nd[node] + bv;
        v = v > 0.f ? v : av * v;
        if (obf) obf[(size_t)node * 256 + tid] = f2bf(v * ns[node]);
        else of[(size_t)node * 256 + tid] = v;
    }
}

// ---------------- launch ----------------

extern "C" void kernel_launch(void* const* d_in, const int* in_sizes, int n_in,
                              void* d_out, int out_size, void* d_ws, size_t ws_size,
                              hipStream_t stream) {
    const float* feat = (const float*)d_in[0];
    const int* src = (const int*)d_in[1];
    const int* dst = (const int*)d_in[2];
    const float* W1 = (const float*)d_in[3];
    const float* b1 = (const float*)d_in[4];
    const float* a1 = (const float*)d_in[5];
    const float* W2 = (const float*)d_in[6];
    const float* b2 = (const float*)d_in[7];
    const float* a2 = (const float*)d_in[8];
    float* out = (float*)d_out;

    const int N = in_sizes[0] / 512;  // 100000
    const int E = in_sizes[1];        // 3200000
    const int NBK = (N + DBK - 1) / DBK;   // 391
    const int NSB = (N + 1023) >> 10;      // 98
    const int NT = (N + TILE - 1) / TILE;  // 1563

    char* ws = (char*)d_ws;
    size_t off = 0;
    auto take = [&](size_t bytes) {
        size_t o = off;
        off += (bytes + 255) & ~(size_t)255;
        return o;
    };
    int* deg_out = (int*)(ws + take((size_t)N * 4));
    int* deg_in = (int*)(ws + take((size_t)N * 4));
    float* nsrc = (float*)(ws + take((size_t)N * 4));
    float* ndst = (float*)(ws + take((size_t)N * 4));
    int* bcnt = (int*)(ws + take((size_t)(NBK + NSB) * 4));
    int* bcntT = bcnt, * bcntS = bcnt + NBK;
    int* tbaseB = (int*)(ws + take((size_t)(NBK + 1) * 4));
    int* tcurB = (int*)(ws + take((size_t)NBK * 4));
    int* sbase = (int*)(ws + take((size_t)(NSB + 1) * 4));
    int* scur = (int*)(ws + take((size_t)NSB * 4));
    int* tstart = (int*)(ws + take((size_t)(NT + 1) * 4));
    int* ekey = (int*)(ws + take((size_t)E * 4));
    u16* W1t = (u16*)(ws + take((size_t)512 * 256 * 2));
    u16* W2t = (u16*)(ws + take((size_t)256 * 256 * 2));
    u16* h = (u16*)(ws + take((size_t)N * 256 * 2));
    u16* x2 = (u16*)(ws + take((size_t)N * 256 * 2));
    int* sb = (int*)x2;  // alias: sb dead before agg1 writes x2 (12.8MB <= 51.2MB)

    hipMemsetAsync(bcnt, 0, (size_t)(NBK + NSB) * 4, stream);

    const int chunk = 8192;
    const int pblocks = (E + chunk - 1) / chunk;  // 391
    bhist_k<<<pblocks, 256, 0, stream>>>(src, dst, bcntT, bcntS, E, chunk, NBK, NSB);
    bscan_k<<<1, 256, 0, stream>>>(bcntT, bcntS, tbaseB, tcurB, sbase, scur, tstart, NBK, NSB, NT, E);
    part_k<<<pblocks, 256, 0, stream>>>(src, dst, tcurB, scur, ekey, sb, E, chunk, NBK, NSB);
    tilesort_k<<<NBK, 256, 0, stream>>>(ekey, tbaseB, tstart, deg_in, NT, N);
    bdeg_k<<<NSB, 256, 0, stream>>>(sb, sbase, deg_out, N);
    norms_k<<<(N + 255) / 256, 256, 0, stream>>>(deg_out, deg_in, nsrc, ndst, N);

    convt_k<<<(512 * 256 + 255) / 256, 256, 0, stream>>>(W1, W1t, 512, 256);
    convt_k<<<(256 * 256 + 255) / 256, 256, 0, stream>>>(W2, W2t, 256, 256);

    dim3 gg((N + 127) / 128);

    // layer 1
    gemm_k<512, true><<<gg, 512, 0, stream>>>(feat, nsrc, W1t, h, N);
    agg2_k<<<NT, 256, 0, stream>>>(h, ekey, tstart, ndst, b1, a1, nsrc, x2, nullptr, N);
    // layer 2
    gemm_k<256, false><<<gg, 512, 0, stream>>>(x2, nullptr, W2t, h, N);
    agg2_k<<<NT, 256, 0, stream>>>(h, ekey, tstart, ndst, b2, a2, nullptr, nullptr, out, N);
}

// Round 11
// 1306.251 us; speedup vs baseline: 1.5227x; 1.5227x over previous
//
#include <hip/hip_runtime.h>
#include <hip/hip_bf16.h>

typedef unsigned short u16;
typedef short s16x8 __attribute__((ext_vector_type(8)));
typedef u16 u16x8 __attribute__((ext_vector_type(8)));
typedef float f32x4 __attribute__((ext_vector_type(4)));

#define DBK 256   // partition/sort bucket = 256 dst
#define TILE 64   // agg tile = 64 dst

__device__ __forceinline__ u16 f2bf(float f) {
    __hip_bfloat16 b = __float2bfloat16(f);
    return __builtin_bit_cast(u16, b);
}
__device__ __forceinline__ float bf2f(u16 u) {
    unsigned int x = ((unsigned int)u) << 16;
    return __builtin_bit_cast(float, x);
}

// ---------------- histogram over dst-buckets (256) and src-buckets (1024) ----------------

__global__ __launch_bounds__(256) void bhist_k(const int* __restrict__ src,
                                               const int* __restrict__ dst,
                                               int* __restrict__ bcntT,
                                               int* __restrict__ bcntS,
                                               int E, int chunk, int NBK, int NSB) {
    __shared__ int hT[400], hS[128];
    const int base = blockIdx.x * chunk;
    const int end = (base + chunk) < E ? (base + chunk) : E;
    for (int i = threadIdx.x; i < NBK; i += 256) hT[i] = 0;
    for (int i = threadIdx.x; i < NSB; i += 256) hS[i] = 0;
    __syncthreads();
    for (int i = base + threadIdx.x; i < end; i += 256) {
        atomicAdd(&hT[dst[i] >> 8], 1);
        atomicAdd(&hS[src[i] >> 10], 1);
    }
    __syncthreads();
    for (int i = threadIdx.x; i < NBK; i += 256)
        if (hT[i]) atomicAdd(&bcntT[i], hT[i]);
    for (int i = threadIdx.x; i < NSB; i += 256)
        if (hS[i]) atomicAdd(&bcntS[i], hS[i]);
}

// single block: exclusive-scan both bucket arrays -> bases + cursors
__global__ void bscan_k(const int* __restrict__ bcntT, const int* __restrict__ bcntS,
                        int* __restrict__ tbaseB, int* __restrict__ tcurB,
                        int* __restrict__ sbase, int* __restrict__ scur,
                        int* __restrict__ tstart, int NBK, int NSB, int NT, int E) {
    __shared__ int part[256];
    __shared__ int arr2[128];
    const int t = threadIdx.x;
    const int i0 = t * 2, i1 = t * 2 + 1;
    int v0 = (i0 < NBK) ? bcntT[i0] : 0;
    int v1 = (i1 < NBK) ? bcntT[i1] : 0;
    part[t] = v0 + v1;
    __syncthreads();
    for (int d = 1; d < 256; d <<= 1) {
        int add = (t >= d) ? part[t - d] : 0;
        __syncthreads();
        part[t] += add;
        __syncthreads();
    }
    int excl = part[t] - (v0 + v1);
    if (i0 < NBK) { tbaseB[i0] = excl; tcurB[i0] = excl; }
    if (i1 < NBK) { tbaseB[i1] = excl + v0; tcurB[i1] = excl + v0; }
    if (t == 0) { tbaseB[NBK] = E; tstart[NT] = E; }
    int vs = (t < NSB) ? bcntS[t] : 0;
    if (t < 128) arr2[t] = vs;
    __syncthreads();
    for (int d = 1; d < 128; d <<= 1) {
        int add = (t >= d && t < 128) ? arr2[t - d] : 0;
        __syncthreads();
        if (t < 128) arr2[t] += add;
        __syncthreads();
    }
    if (t < NSB) { int e2 = arr2[t] - vs; sbase[t] = e2; scur[t] = e2; }
    if (t == 0) sbase[NSB] = E;
}

// partition: scatter packed keys by dst-bucket, src values by src-bucket
// key = (tile_local<<23) | (src<<6) | dst_local  (2+17+6 = 25 bits)
__global__ __launch_bounds__(256) void part_k(const int* __restrict__ src,
                                              const int* __restrict__ dst,
                                              int* __restrict__ tcurB,
                                              int* __restrict__ scur,
                                              int* __restrict__ ekey,
                                              int* __restrict__ sb,
                                              int E, int chunk, int NBK, int NSB) {
    __shared__ int hT[400], hS[128];
    const int base = blockIdx.x * chunk;
    const int end = (base + chunk) < E ? (base + chunk) : E;
    for (int i = threadIdx.x; i < NBK; i += 256) hT[i] = 0;
    for (int i = threadIdx.x; i < NSB; i += 256) hS[i] = 0;
    __syncthreads();
    for (int i = base + threadIdx.x; i < end; i += 256) {
        atomicAdd(&hT[dst[i] >> 8], 1);
        atomicAdd(&hS[src[i] >> 10], 1);
    }
    __syncthreads();
    for (int i = threadIdx.x; i < NBK; i += 256) {
        int c = hT[i];
        hT[i] = c ? atomicAdd(&tcurB[i], c) : 0;
    }
    for (int i = threadIdx.x; i < NSB; i += 256) {
        int c = hS[i];
        hS[i] = c ? atomicAdd(&scur[i], c) : 0;
    }
    __syncthreads();
    for (int i = base + threadIdx.x; i < end; i += 256) {
        int d = dst[i], s = src[i];
        int pos = atomicAdd(&hT[d >> 8], 1);
        ekey[pos] = (((d & 255) >> 6) << 23) | (s << 6) | (d & 63);
        int pos2 = atomicAdd(&hS[s >> 10], 1);
        sb[pos2] = s;
    }
}

// ---------------- blocked STABLE radix sort per bucket (determinism + src order) ----------------
// 5 passes x 5 bits. Per-thread-column LDS histograms (no atomics), block scan,
// stable scatter to ping-pong buffer (32KB window => L2-resident). Stable sort
// => canonical sorted output independent of part_k's atomic write order.

__global__ __launch_bounds__(256) void radix_k(const int* __restrict__ in,
                                               int* __restrict__ outb,
                                               const int* __restrict__ tbaseB,
                                               int shift) {
    __shared__ int hist[32 * 256];
    __shared__ int part[256];
    const int b = blockIdx.x, t = threadIdx.x;
    const int beg = tbaseB[b], end = tbaseB[b + 1];
    const int L = end - beg;
    const int C = (L + 255) >> 8;
    const int s0 = t * C;
    const int s1 = (s0 + C) < L ? (s0 + C) : L;
    for (int i = t; i < 32 * 256; i += 256) hist[i] = 0;
    __syncthreads();
    for (int i = s0; i < s1; ++i) {
        int dig = (in[beg + i] >> shift) & 31;
        hist[dig * 256 + t]++;  // own column: no atomic needed
    }
    __syncthreads();
    // exclusive scan of hist[8192] in (digit-major, thread) order
    const int u0 = t * 32;
    int loc[32];
    int sum = 0;
#pragma unroll
    for (int j = 0; j < 32; ++j) { loc[j] = sum; sum += hist[u0 + j]; }
    part[t] = sum;
    __syncthreads();
    int pv = part[t];
    for (int d = 1; d < 256; d <<= 1) {
        int add = (t >= d) ? part[t - d] : 0;
        __syncthreads();
        part[t] += add;
        __syncthreads();
    }
    const int base = part[t] - pv;
#pragma unroll
    for (int j = 0; j < 32; ++j) hist[u0 + j] = base + loc[j];
    __syncthreads();
    // stable scatter (cursor column owned by this thread)
    for (int i = s0; i < s1; ++i) {
        int k = in[beg + i];
        int c = ((k >> shift) & 31) * 256 + t;
        int pos = hist[c]++;
        outb[beg + pos] = k;
    }
}

// per dst-bucket: dl-histogram on sorted keys -> deg_in + per-tile starts
__global__ __launch_bounds__(256) void tpost_k(const int* __restrict__ skey,
                                               const int* __restrict__ tbaseB,
                                               int* __restrict__ tstart,
                                               int* __restrict__ din,
                                               int NT, int N) {
    __shared__ int h64[256];
    __shared__ int tc[4];
    const int b = blockIdx.x, tid = threadIdx.x;
    const int beg = tbaseB[b], end = tbaseB[b + 1];
    const int L = end - beg;
    h64[tid] = 0;
    if (tid < 4) tc[tid] = 0;
    __syncthreads();
    for (int i = tid; i < L; i += 256) {
        int k = skey[beg + i];
        atomicAdd(&h64[((k >> 23) & 3) * 64 + (k & 63)], 1);
    }
    __syncthreads();
    {
        int node = b * DBK + tid;
        if (node < N) din[node] = h64[tid];
    }
    if (tid < 4) {
        int s = 0;
#pragma unroll
        for (int x = 0; x < 64; x++) s += h64[tid * 64 + x];
        tc[tid] = s;
    }
    __syncthreads();
    if (tid < 4) {
        int p = beg;
        for (int x = 0; x < tid; x++) p += tc[x];
        int ti = b * 4 + tid;
        if (ti <= NT) tstart[ti] = p;
    }
}

// per src-bucket: LDS histogram -> deg_out (dense)
__global__ __launch_bounds__(256) void bdeg_k(const int* __restrict__ sb,
                                              const int* __restrict__ sbase,
                                              int* __restrict__ dout, int N) {
    __shared__ int hist[1024];
    const int b = blockIdx.x;
    const int beg = sbase[b], end = sbase[b + 1];
    const int nbase = b << 10;
    const int nlen = (N - nbase) < 1024 ? (N - nbase) : 1024;
    for (int i = threadIdx.x; i < 1024; i += 256) hist[i] = 0;
    __syncthreads();
    for (int i = beg + threadIdx.x; i < end; i += 256)
        atomicAdd(&hist[sb[i] - nbase], 1);
    __syncthreads();
    for (int i = threadIdx.x; i < nlen; i += 256) dout[nbase + i] = hist[i];
}

__global__ void norms_k(const int* __restrict__ dout, const int* __restrict__ din,
                        float* __restrict__ ns, float* __restrict__ nd, int n) {
    int i = blockIdx.x * blockDim.x + threadIdx.x;
    if (i < n) {
        ns[i] = 1.0f / sqrtf(fmaxf((float)dout[i], 1.0f));
        nd[i] = 1.0f / sqrtf(fmaxf((float)din[i], 1.0f));
    }
}

__global__ void convt_k(const float* __restrict__ W, u16* __restrict__ Wt, int K, int Nn) {
    int i = blockIdx.x * blockDim.x + threadIdx.x;
    if (i < K * Nn) {
        int n = i / K, k = i - n * K;
        Wt[i] = f2bf(W[(size_t)k * Nn + n]);
    }
}

// ---------------- GEMM: C[M][256] = A(scaled,bf16) @ W, tile 128x256x64, 8 waves ----------------

template <int K, bool AF32>
__global__ __launch_bounds__(512) void gemm_k(const void* __restrict__ Ap,
                                              const float* __restrict__ nsrc,
                                              const u16* __restrict__ Bt,
                                              u16* __restrict__ C, int M) {
    constexpr int BKt = 64;
    __shared__ u16 Al[128 * BKt];
    __shared__ u16 Bl[256 * BKt];
    const int tid = threadIdx.x, lane = tid & 63, wid = tid >> 6;
    const int wr = wid >> 2, wc = wid & 3;
    const int l15 = lane & 15, lhi = lane >> 4;
    const int bm = blockIdx.x * 128;
    f32x4 acc[4][4] = {};

    for (int k0 = 0; k0 < K; k0 += BKt) {
#pragma unroll
        for (int i = 0; i < 2; i++) {
            int G = i * 512 + tid, row = G >> 3, gk = G & 7;
            int grow = bm + row;
            grow = grow < M ? grow : M - 1;
            u16x8 w;
            if constexpr (AF32) {
                const float* A = (const float*)Ap;
                const f32x4 v0 = *(const f32x4*)(A + (size_t)grow * K + k0 + gk * 8);
                const f32x4 v1 = *(const f32x4*)(A + (size_t)grow * K + k0 + gk * 8 + 4);
                const float ns = nsrc[grow];
                w[0] = f2bf(v0[0] * ns); w[1] = f2bf(v0[1] * ns);
                w[2] = f2bf(v0[2] * ns); w[3] = f2bf(v0[3] * ns);
                w[4] = f2bf(v1[0] * ns); w[5] = f2bf(v1[1] * ns);
                w[6] = f2bf(v1[2] * ns); w[7] = f2bf(v1[3] * ns);
            } else {
                const u16* A = (const u16*)Ap;
                w = *(const u16x8*)(A + (size_t)grow * K + k0 + gk * 8);
            }
            int idx = (row * BKt + gk * 8) ^ ((row & 7) << 3);
            *(u16x8*)(Al + idx) = w;
        }
#pragma unroll
        for (int i = 0; i < 4; i++) {
            int G = i * 512 + tid, row = G >> 3, gk = G & 7;
            u16x8 wb = *(const u16x8*)(Bt + (size_t)row * K + k0 + gk * 8);
            int idx = (row * BKt + gk * 8) ^ ((row & 7) << 3);
            *(u16x8*)(Bl + idx) = wb;
        }
        __syncthreads();

        s16x8 af[2][4], bfr[2][4];
#pragma unroll
        for (int kk = 0; kk < 2; kk++) {
#pragma unroll
            for (int mi = 0; mi < 4; mi++) {
                int row = wr * 64 + mi * 16 + l15;
                int idx = (row * BKt + kk * 32 + lhi * 8) ^ ((row & 7) << 3);
                af[kk][mi] = *(const s16x8*)(Al + idx);
            }
#pragma unroll
            for (int ni = 0; ni < 4; ni++) {
                int n = wc * 64 + ni * 16 + l15;
                int idx = (n * BKt + kk * 32 + lhi * 8) ^ ((n & 7) << 3);
                bfr[kk][ni] = *(const s16x8*)(Bl + idx);
            }
        }
#pragma unroll
        for (int kk = 0; kk < 2; kk++)
#pragma unroll
            for (int mi = 0; mi < 4; mi++)
#pragma unroll
                for (int ni = 0; ni < 4; ni++)
                    acc[mi][ni] = __builtin_amdgcn_mfma_f32_16x16x32_bf16(
                        af[kk][mi], bfr[kk][ni], acc[mi][ni], 0, 0, 0);
        __syncthreads();
    }

#pragma unroll
    for (int mi = 0; mi < 4; mi++) {
#pragma unroll
        for (int r = 0; r < 4; r++) {
            int grow = bm + wr * 64 + mi * 16 + lhi * 4 + r;
            if (grow < M) {
#pragma unroll
                for (int ni = 0; ni < 4; ni++) {
                    int gcol = wc * 64 + ni * 16 + l15;
                    C[(size_t)grow * 256 + gcol] = f2bf(acc[mi][ni][r]);
                }
            }
        }
    }
}

// ---------------- aggregation: cache-blocked src-sorted sweep ----------------
// Block = 64-dst tile; acc[64][256] f32 in LDS; thread = channel.
// Edges sorted by (tile, src) — concurrent blocks sweep src space in phase.
// Manually inlined double-buffered 8-edge batches (no lambdas: rule #20 —
// pointer-passed local arrays spill to scratch). XCD-bijective block swizzle.

__global__ __launch_bounds__(256) void agg2_k(const u16* __restrict__ h,
                                              const int* __restrict__ skey,
                                              const int* __restrict__ tstart,
                                              const float* __restrict__ nd,
                                              const float* __restrict__ bias,
                                              const float* __restrict__ alpha,
                                              const float* __restrict__ ns,
                                              u16* __restrict__ obf, float* __restrict__ of,
                                              int n, int NT) {
    __shared__ float acc[TILE * 256];  // 64KB
    __shared__ int kb[1024];           // 4KB
    // bijective XCD swizzle (m204): adjacent tiles share an XCD's L2
    const int orig = blockIdx.x;
    const int q = NT >> 3, r = NT & 7, xcd = orig & 7;
    const int t = (xcd < r ? xcd * (q + 1) : r * (q + 1) + (xcd - r) * q) + (orig >> 3);
    const int tid = threadIdx.x;
    const int beg = tstart[t], end = tstart[t + 1];
    for (int i = tid; i < TILE * 256; i += 256) acc[i] = 0.f;
    const float bv = bias[tid], av = alpha[tid];
    __syncthreads();

    for (int ch = beg; ch < end; ch += 1024) {
        const int m = (end - ch) < 1024 ? (end - ch) : 1024;
        for (int i = tid; i < m; i += 256) kb[i] = skey[ch + i];
        __syncthreads();
        int e = 0;
        if (m >= 16) {
            int dA[8]; float xA[8];
#pragma unroll
            for (int u = 0; u < 8; u++) {
                int k = kb[u];
                dA[u] = (k & 63) << 8;
                xA[u] = bf2f(h[(size_t)((k >> 6) & 0x1FFFF) * 256 + tid]);
            }
            e = 8;
            for (; e + 15 < m; e += 16) {
                int dB[8]; float xB[8];
#pragma unroll
                for (int u = 0; u < 8; u++) {
                    int k = kb[e + u];
                    dB[u] = (k & 63) << 8;
                    xB[u] = bf2f(h[(size_t)((k >> 6) & 0x1FFFF) * 256 + tid]);
                }
#pragma unroll
                for (int u = 0; u < 8; u++) acc[dA[u] + tid] += xA[u];
#pragma unroll
                for (int u = 0; u < 8; u++) {
                    int k = kb[e + 8 + u];
                    dA[u] = (k & 63) << 8;
                    xA[u] = bf2f(h[(size_t)((k >> 6) & 0x1FFFF) * 256 + tid]);
                }
#pragma unroll
                for (int u = 0; u < 8; u++) acc[dB[u] + tid] += xB[u];
            }
            if (e + 7 < m) {
                int dB[8]; float xB[8];
#pragma unroll
                for (int u = 0; u < 8; u++) {
                    int k = kb[e + u];
                    dB[u] = (k & 63) << 8;
                    xB[u] = bf2f(h[(size_t)((k >> 6) & 0x1FFFF) * 256 + tid]);
                }
#pragma unroll
                for (int u = 0; u < 8; u++) acc[dA[u] + tid] += xA[u];
#pragma unroll
                for (int u = 0; u < 8; u++) acc[dB[u] + tid] += xB[u];
                e += 8;
            } else {
#pragma unroll
                for (int u = 0; u < 8; u++) acc[dA[u] + tid] += xA[u];
            }
        }
        for (; e < m; ++e) {
            int k = kb[e];
            acc[((k & 63) << 8) + tid] += bf2f(h[(size_t)((k >> 6) & 0x1FFFF) * 256 + tid]);
        }
        __syncthreads();
    }

    // epilogue: norm_dst, bias, PReLU, [x norm_src -> bf16]
    for (int dl = 0; dl < TILE; ++dl) {
        int node = t * TILE + dl;
        if (node >= n) break;
        float v = acc[dl * 256 + tid] * nd[node] + bv;
        v = v > 0.f ? v : av * v;
        if (obf) obf[(size_t)node * 256 + tid] = f2bf(v * ns[node]);
        else of[(size_t)node * 256 + tid] = v;
    }
}

// ---------------- launch ----------------

extern "C" void kernel_launch(void* const* d_in, const int* in_sizes, int n_in,
                              void* d_out, int out_size, void* d_ws, size_t ws_size,
                              hipStream_t stream) {
    const float* feat = (const float*)d_in[0];
    const int* src = (const int*)d_in[1];
    const int* dst = (const int*)d_in[2];
    const float* W1 = (const float*)d_in[3];
    const float* b1 = (const float*)d_in[4];
    const float* a1 = (const float*)d_in[5];
    const float* W2 = (const float*)d_in[6];
    const float* b2 = (const float*)d_in[7];
    const float* a2 = (const float*)d_in[8];
    float* out = (float*)d_out;

    const int N = in_sizes[0] / 512;  // 100000
    const int E = in_sizes[1];        // 3200000
    const int NBK = (N + DBK - 1) / DBK;   // 391
    const int NSB = (N + 1023) >> 10;      // 98
    const int NT = (N + TILE - 1) / TILE;  // 1563

    char* ws = (char*)d_ws;
    size_t off = 0;
    auto take = [&](size_t bytes) {
        size_t o = off;
        off += (bytes + 255) & ~(size_t)255;
        return o;
    };
    int* deg_out = (int*)(ws + take((size_t)N * 4));
    int* deg_in = (int*)(ws + take((size_t)N * 4));
    float* nsrc = (float*)(ws + take((size_t)N * 4));
    float* ndst = (float*)(ws + take((size_t)N * 4));
    int* bcnt = (int*)(ws + take((size_t)(NBK + NSB) * 4));
    int* bcntT = bcnt, * bcntS = bcnt + NBK;
    int* tbaseB = (int*)(ws + take((size_t)(NBK + 1) * 4));
    int* tcurB = (int*)(ws + take((size_t)NBK * 4));
    int* sbase = (int*)(ws + take((size_t)(NSB + 1) * 4));
    int* scur = (int*)(ws + take((size_t)NSB * 4));
    int* tstart = (int*)(ws + take((size_t)(NT + 1) * 4));
    int* ekey = (int*)(ws + take((size_t)E * 4));
    int* ealt = (int*)(ws + take((size_t)E * 4));
    u16* W1t = (u16*)(ws + take((size_t)512 * 256 * 2));
    u16* W2t = (u16*)(ws + take((size_t)256 * 256 * 2));
    u16* h = (u16*)(ws + take((size_t)N * 256 * 2));
    u16* x2 = (u16*)(ws + take((size_t)N * 256 * 2));
    int* sb = (int*)x2;  // alias: sb dead before agg1 writes x2

    hipMemsetAsync(bcnt, 0, (size_t)(NBK + NSB) * 4, stream);

    const int chunk = 8192;
    const int pblocks = (E + chunk - 1) / chunk;
    bhist_k<<<pblocks, 256, 0, stream>>>(src, dst, bcntT, bcntS, E, chunk, NBK, NSB);
    bscan_k<<<1, 256, 0, stream>>>(bcntT, bcntS, tbaseB, tcurB, sbase, scur, tstart, NBK, NSB, NT, E);
    part_k<<<pblocks, 256, 0, stream>>>(src, dst, tcurB, scur, ekey, sb, E, chunk, NBK, NSB);
    // stable radix: 5 passes x 5 bits; final sorted keys land in ealt
    radix_k<<<NBK, 256, 0, stream>>>(ekey, ealt, tbaseB, 0);
    radix_k<<<NBK, 256, 0, stream>>>(ealt, ekey, tbaseB, 5);
    radix_k<<<NBK, 256, 0, stream>>>(ekey, ealt, tbaseB, 10);
    radix_k<<<NBK, 256, 0, stream>>>(ealt, ekey, tbaseB, 15);
    radix_k<<<NBK, 256, 0, stream>>>(ekey, ealt, tbaseB, 20);
    tpost_k<<<NBK, 256, 0, stream>>>(ealt, tbaseB, tstart, deg_in, NT, N);
    bdeg_k<<<NSB, 256, 0, stream>>>(sb, sbase, deg_out, N);
    norms_k<<<(N + 255) / 256, 256, 0, stream>>>(deg_out, deg_in, nsrc, ndst, N);

    convt_k<<<(512 * 256 + 255) / 256, 256, 0, stream>>>(W1, W1t, 512, 256);
    convt_k<<<(256 * 256 + 255) / 256, 256, 0, stream>>>(W2, W2t, 256, 256);

    dim3 gg((N + 127) / 128);

    // layer 1
    gemm_k<512, true><<<gg, 512, 0, stream>>>(feat, nsrc, W1t, h, N);
    agg2_k<<<NT, 256, 0, stream>>>(h, ealt, tstart, ndst, b1, a1, nsrc, x2, nullptr, N, NT);
    // layer 2
    gemm_k<256, false><<<gg, 512, 0, stream>>>(x2, nullptr, W2t, h, N);
    agg2_k<<<NT, 256, 0, stream>>>(h, ealt, tstart, ndst, b2, a2, nullptr, nullptr, out, N, NT);
}

// Round 12
// 815.593 us; speedup vs baseline: 2.4387x; 1.6016x over previous
//
#include <hip/hip_runtime.h>
#include <hip/hip_bf16.h>

typedef unsigned short u16;
typedef short s16x8 __attribute__((ext_vector_type(8)));
typedef u16 u16x8 __attribute__((ext_vector_type(8)));
typedef float f32x4 __attribute__((ext_vector_type(4)));

#define BSHIFT 10  // bucket = node >> 10 (1024 nodes per bucket)

__device__ __forceinline__ u16 f2bf(float f) {
    __hip_bfloat16 b = __float2bfloat16(f);
    return __builtin_bit_cast(u16, b);
}
__device__ __forceinline__ float bf2f(u16 u) {
    unsigned int x = ((unsigned int)u) << 16;
    return __builtin_bit_cast(float, x);
}

// ---------------- bucket histogram (coarse, both src and dst) ----------------

__global__ __launch_bounds__(256) void bhist_k(const int* __restrict__ src,
                                               const int* __restrict__ dst,
                                               int* __restrict__ bcntA,  // dst buckets
                                               int* __restrict__ bcntB,  // src buckets
                                               int E, int chunk) {
    __shared__ int hA[128], hB[128];
    const int base = blockIdx.x * chunk;
    const int end = (base + chunk) < E ? (base + chunk) : E;
    if (threadIdx.x < 128) { hA[threadIdx.x] = 0; hB[threadIdx.x] = 0; }
    __syncthreads();
    for (int i = base + threadIdx.x; i < end; i += 256) {
        atomicAdd(&hA[dst[i] >> BSHIFT], 1);
        atomicAdd(&hB[src[i] >> BSHIFT], 1);
    }
    __syncthreads();
    if (threadIdx.x < 128) {
        if (hA[threadIdx.x]) atomicAdd(&bcntA[threadIdx.x], hA[threadIdx.x]);
        if (hB[threadIdx.x]) atomicAdd(&bcntB[threadIdx.x], hB[threadIdx.x]);
    }
}

// single block: scan both bucket-count arrays -> bases, init cursors
__global__ void bscan_k(const int* __restrict__ bcntA, const int* __restrict__ bcntB,
                        int* __restrict__ bbaseA, int* __restrict__ bbaseB,
                        int* __restrict__ bcurA, int* __restrict__ bcurB,
                        int* __restrict__ row_ptr, int NB, int N, int E) {
    __shared__ int tA[128], tB[128];
    const int t = threadIdx.x;
    int vA = (t < NB) ? bcntA[t] : 0;
    int vB = (t < NB) ? bcntB[t] : 0;
    tA[t] = vA; tB[t] = vB;
    __syncthreads();
    for (int d = 1; d < 128; d <<= 1) {
        int aA = (t >= d) ? tA[t - d] : 0;
        int aB = (t >= d) ? tB[t - d] : 0;
        __syncthreads();
        tA[t] += aA; tB[t] += aB;
        __syncthreads();
    }
    if (t < NB) {
        int eA = tA[t] - vA, eB = tB[t] - vB;
        bbaseA[t] = eA; bcurA[t] = eA;
        bbaseB[t] = eB; bcurB[t] = eB;
    } else if (t == NB) {
        bbaseA[NB] = E; bbaseB[NB] = E;
    }
    if (t == 0) row_ptr[N] = E;
}

// partition: scatter packed key (src<<10 | dst_local) by dst-bucket, src by src-bucket
__global__ __launch_bounds__(256) void part_k(const int* __restrict__ src,
                                              const int* __restrict__ dst,
                                              int* __restrict__ bcurA,
                                              int* __restrict__ bcurB,
                                              int* __restrict__ kcode,
                                              int* __restrict__ sb,
                                              int E, int chunk) {
    __shared__ int hA[128], hB[128];
    const int base = blockIdx.x * chunk;
    const int end = (base + chunk) < E ? (base + chunk) : E;
    if (threadIdx.x < 128) { hA[threadIdx.x] = 0; hB[threadIdx.x] = 0; }
    __syncthreads();
    for (int i = base + threadIdx.x; i < end; i += 256) {
        atomicAdd(&hA[dst[i] >> BSHIFT], 1);
        atomicAdd(&hB[src[i] >> BSHIFT], 1);
    }
    __syncthreads();
    if (threadIdx.x < 128) {
        int c = hA[threadIdx.x];
        hA[threadIdx.x] = c ? atomicAdd(&bcurA[threadIdx.x], c) : 0;
        c = hB[threadIdx.x];
        hB[threadIdx.x] = c ? atomicAdd(&bcurB[threadIdx.x], c) : 0;
    }
    __syncthreads();
    for (int i = base + threadIdx.x; i < end; i += 256) {
        int d = dst[i], s = src[i];
        int posA = atomicAdd(&hA[d >> BSHIFT], 1);
        kcode[posA] = (s << BSHIFT) | (d & 1023);
        int posB = atomicAdd(&hB[s >> BSHIFT], 1);
        sb[posB] = s;
    }
}

// per dst-bucket: LDS histogram -> deg_in + row_ptr (dense), then CSR col scatter
__global__ __launch_bounds__(256) void bcsr_k(const int* __restrict__ kcode,
                                              const int* __restrict__ bbase,
                                              int* __restrict__ row_ptr,
                                              int* __restrict__ din,
                                              int* __restrict__ col, int N) {
    __shared__ int hist[1024];
    __shared__ int cur[1024];
    __shared__ int psum[256];
    const int b = blockIdx.x;
    const int beg = bbase[b], end = bbase[b + 1];
    const int nbase = b << BSHIFT;
    const int nlen = (N - nbase) < 1024 ? (N - nbase) : 1024;
    const int t = threadIdx.x;
#pragma unroll
    for (int j = 0; j < 4; j++) hist[t * 4 + j] = 0;
    __syncthreads();
    for (int i = beg + t; i < end; i += 256)
        atomicAdd(&hist[kcode[i] & 1023], 1);
    __syncthreads();
    int h0 = hist[4 * t], h1 = hist[4 * t + 1], h2 = hist[4 * t + 2], h3 = hist[4 * t + 3];
    int s = h0 + h1 + h2 + h3;
    psum[t] = s;
    __syncthreads();
    for (int d = 1; d < 256; d <<= 1) {
        int add = (t >= d) ? psum[t - d] : 0;
        __syncthreads();
        psum[t] += add;
        __syncthreads();
    }
    int e0 = psum[t] - s;
    int e1 = e0 + h0, e2 = e1 + h1, e3 = e2 + h2;
    cur[4 * t] = beg + e0; cur[4 * t + 1] = beg + e1;
    cur[4 * t + 2] = beg + e2; cur[4 * t + 3] = beg + e3;
    if (4 * t + 0 < nlen) { row_ptr[nbase + 4 * t + 0] = beg + e0; din[nbase + 4 * t + 0] = h0; }
    if (4 * t + 1 < nlen) { row_ptr[nbase + 4 * t + 1] = beg + e1; din[nbase + 4 * t + 1] = h1; }
    if (4 * t + 2 < nlen) { row_ptr[nbase + 4 * t + 2] = beg + e2; din[nbase + 4 * t + 2] = h2; }
    if (4 * t + 3 < nlen) { row_ptr[nbase + 4 * t + 3] = beg + e3; din[nbase + 4 * t + 3] = h3; }
    __syncthreads();
    for (int i = beg + t; i < end; i += 256) {
        int k = kcode[i];
        int pos = atomicAdd(&cur[k & 1023], 1);
        col[pos] = k >> BSHIFT;
    }
}

// per src-bucket: LDS histogram -> deg_out (dense)
__global__ __launch_bounds__(256) void bdeg_k(const int* __restrict__ sb,
                                              const int* __restrict__ bbase,
                                              int* __restrict__ dout, int N) {
    __shared__ int hist[1024];
    const int b = blockIdx.x;
    const int beg = bbase[b], end = bbase[b + 1];
    const int nbase = b << BSHIFT;
    const int nlen = (N - nbase) < 1024 ? (N - nbase) : 1024;
    for (int i = threadIdx.x; i < 1024; i += 256) hist[i] = 0;
    __syncthreads();
    for (int i = beg + threadIdx.x; i < end; i += 256)
        atomicAdd(&hist[sb[i] - nbase], 1);
    __syncthreads();
    for (int i = threadIdx.x; i < nlen; i += 256) dout[nbase + i] = hist[i];
}

// ---------------- per-row sort of col (DETERMINISM) ----------------
// CSR scatter order is atomic-schedule-dependent; sorted rows give a canonical
// edge order so every replay sums in the same order (bit-identical output).
__global__ __launch_bounds__(256) void sortrow_k(const int* __restrict__ rp,
                                                 int* __restrict__ col, int n) {
    int w = (blockIdx.x * blockDim.x + threadIdx.x) >> 6;
    if (w >= n) return;
    const int lane = threadIdx.x & 63;
    const int beg = rp[w], end = rp[w + 1];
    const int deg = end - beg;
    if (deg <= 1) return;
    if (deg <= 128) {
        const int INF = 0x7fffffff;
        int a = (lane < deg) ? col[beg + lane] : INF;
        int b = (64 + lane < deg) ? col[beg + 64 + lane] : INF;
#pragma unroll
        for (int k = 2; k <= 128; k <<= 1) {
#pragma unroll
            for (int j = k >> 1; j > 0; j >>= 1) {
                if (j >= 64) {
                    int lo = a < b ? a : b, hi = a < b ? b : a;
                    a = lo; b = hi;
                } else {
                    int pa = __shfl_xor(a, j);
                    int pb = __shfl_xor(b, j);
                    bool lower = ((lane & j) == 0);
                    bool asc_a = ((lane & k) == 0);
                    bool asc_b = (((lane + 64) & k) == 0);
                    int mna = a < pa ? a : pa, mxa = a < pa ? pa : a;
                    int mnb = b < pb ? b : pb, mxb = b < pb ? pb : b;
                    a = (lower == asc_a) ? mna : mxa;
                    b = (lower == asc_b) ? mnb : mxb;
                }
            }
        }
        if (lane < deg) col[beg + lane] = a;
        if (64 + lane < deg) col[beg + 64 + lane] = b;
    } else if (lane == 0) {
        for (int i = beg + 1; i < end; i++) {
            int v = col[i], j = i - 1;
            while (j >= beg && col[j] > v) { col[j + 1] = col[j]; j--; }
            col[j + 1] = v;
        }
    }
}

__global__ void norms_k(const int* __restrict__ dout, const int* __restrict__ din,
                        float* __restrict__ ns, float* __restrict__ nd, int n) {
    int i = blockIdx.x * blockDim.x + threadIdx.x;
    if (i < n) {
        ns[i] = 1.0f / sqrtf(fmaxf((float)dout[i], 1.0f));
        nd[i] = 1.0f / sqrtf(fmaxf((float)din[i], 1.0f));
    }
}

// transpose-convert W[k][n] (f32) -> Wt[n][k] (bf16)
__global__ void convt_k(const float* __restrict__ W, u16* __restrict__ Wt, int K, int Nn) {
    int i = blockIdx.x * blockDim.x + threadIdx.x;
    if (i < K * Nn) {
        int n = i / K, k = i - n * K;
        Wt[i] = f2bf(W[(size_t)k * Nn + n]);
    }
}

// ---------------- GEMM: C[M][256] = A(scaled,bf16) @ W, tile 128x256x64, 8 waves ----------------

template <int K, bool AF32>
__global__ __launch_bounds__(512) void gemm_k(const void* __restrict__ Ap,
                                              const float* __restrict__ nsrc,
                                              const u16* __restrict__ Bt,
                                              u16* __restrict__ C, int M) {
    constexpr int BKt = 64;
    __shared__ u16 Al[128 * BKt];
    __shared__ u16 Bl[256 * BKt];
    const int tid = threadIdx.x, lane = tid & 63, wid = tid >> 6;
    const int wr = wid >> 2, wc = wid & 3;
    const int l15 = lane & 15, lhi = lane >> 4;
    const int bm = blockIdx.x * 128;
    f32x4 acc[4][4] = {};

    for (int k0 = 0; k0 < K; k0 += BKt) {
#pragma unroll
        for (int i = 0; i < 2; i++) {
            int G = i * 512 + tid, row = G >> 3, gk = G & 7;
            int grow = bm + row;
            grow = grow < M ? grow : M - 1;
            u16x8 w;
            if constexpr (AF32) {
                const float* A = (const float*)Ap;
                const f32x4 v0 = *(const f32x4*)(A + (size_t)grow * K + k0 + gk * 8);
                const f32x4 v1 = *(const f32x4*)(A + (size_t)grow * K + k0 + gk * 8 + 4);
                const float ns = nsrc[grow];
                w[0] = f2bf(v0[0] * ns); w[1] = f2bf(v0[1] * ns);
                w[2] = f2bf(v0[2] * ns); w[3] = f2bf(v0[3] * ns);
                w[4] = f2bf(v1[0] * ns); w[5] = f2bf(v1[1] * ns);
                w[6] = f2bf(v1[2] * ns); w[7] = f2bf(v1[3] * ns);
            } else {
                const u16* A = (const u16*)Ap;
                w = *(const u16x8*)(A + (size_t)grow * K + k0 + gk * 8);
            }
            int idx = (row * BKt + gk * 8) ^ ((row & 7) << 3);
            *(u16x8*)(Al + idx) = w;
        }
#pragma unroll
        for (int i = 0; i < 4; i++) {
            int G = i * 512 + tid, row = G >> 3, gk = G & 7;
            u16x8 wb = *(const u16x8*)(Bt + (size_t)row * K + k0 + gk * 8);
            int idx = (row * BKt + gk * 8) ^ ((row & 7) << 3);
            *(u16x8*)(Bl + idx) = wb;
        }
        __syncthreads();

        s16x8 af[2][4], bfr[2][4];
#pragma unroll
        for (int kk = 0; kk < 2; kk++) {
#pragma unroll
            for (int mi = 0; mi < 4; mi++) {
                int row = wr * 64 + mi * 16 + l15;
                int idx = (row * BKt + kk * 32 + lhi * 8) ^ ((row & 7) << 3);
                af[kk][mi] = *(const s16x8*)(Al + idx);
            }
#pragma unroll
            for (int ni = 0; ni < 4; ni++) {
                int n = wc * 64 + ni * 16 + l15;
                int idx = (n * BKt + kk * 32 + lhi * 8) ^ ((n & 7) << 3);
                bfr[kk][ni] = *(const s16x8*)(Bl + idx);
            }
        }
#pragma unroll
        for (int kk = 0; kk < 2; kk++)
#pragma unroll
            for (int mi = 0; mi < 4; mi++)
#pragma unroll
                for (int ni = 0; ni < 4; ni++)
                    acc[mi][ni] = __builtin_amdgcn_mfma_f32_16x16x32_bf16(
                        af[kk][mi], bfr[kk][ni], acc[mi][ni], 0, 0, 0);
        __syncthreads();
    }

#pragma unroll
    for (int mi = 0; mi < 4; mi++) {
#pragma unroll
        for (int r = 0; r < 4; r++) {
            int grow = bm + wr * 64 + mi * 16 + lhi * 4 + r;
            if (grow < M) {
#pragma unroll
                for (int ni = 0; ni < 4; ni++) {
                    int gcol = wc * 64 + ni * 16 + l15;
                    C[(size_t)grow * 256 + gcol] = f2bf(acc[mi][ni][r]);
                }
            }
        }
    }
}

// ---------------- pull aggregation (R4 form: best measured, 219us) ----------------
// One node per 32-lane half (2 nodes/wave). lane covers 8 channels (16B);
// 8 gathers (4KB) issued per iteration across 4 independent chains.
// Low VGPR (~40) -> high occupancy; wave count does the latency hiding.

__global__ __launch_bounds__(256) void agg_k(const u16* __restrict__ h,
                                             const int* __restrict__ rp,
                                             const int* __restrict__ col,
                                             const float* __restrict__ nd,
                                             const float* __restrict__ bias,
                                             const float* __restrict__ alpha,
                                             const float* __restrict__ ns,
                                             u16* __restrict__ obf, float* __restrict__ of,
                                             int n) {
    int w = (blockIdx.x * blockDim.x + threadIdx.x) >> 5;
    if (w >= n) return;
    const int c0 = (threadIdx.x & 31) * 8;
    const int beg = rp[w], end = rp[w + 1];

    float a0[8] = {}, a1[8] = {}, a2[8] = {}, a3[8] = {};

    int p = beg;
    for (; p + 7 < end; p += 8) {
        int s0 = col[p], s1 = col[p + 1], s2 = col[p + 2], s3 = col[p + 3];
        int s4 = col[p + 4], s5 = col[p + 5], s6 = col[p + 6], s7 = col[p + 7];
        u16x8 v0 = *(const u16x8*)(h + (size_t)s0 * 256 + c0);
        u16x8 v1 = *(const u16x8*)(h + (size_t)s1 * 256 + c0);
        u16x8 v2 = *(const u16x8*)(h + (size_t)s2 * 256 + c0);
        u16x8 v3 = *(const u16x8*)(h + (size_t)s3 * 256 + c0);
        u16x8 v4 = *(const u16x8*)(h + (size_t)s4 * 256 + c0);
        u16x8 v5 = *(const u16x8*)(h + (size_t)s5 * 256 + c0);
        u16x8 v6 = *(const u16x8*)(h + (size_t)s6 * 256 + c0);
        u16x8 v7 = *(const u16x8*)(h + (size_t)s7 * 256 + c0);
#pragma unroll
        for (int j = 0; j < 8; j++) {
            a0[j] += bf2f(v0[j]);
            a1[j] += bf2f(v1[j]);
            a2[j] += bf2f(v2[j]);
            a3[j] += bf2f(v3[j]);
        }
#pragma unroll
        for (int j = 0; j < 8; j++) {
            a0[j] += bf2f(v4[j]);
            a1[j] += bf2f(v5[j]);
            a2[j] += bf2f(v6[j]);
            a3[j] += bf2f(v7[j]);
        }
    }
    for (; p + 3 < end; p += 4) {
        int s0 = col[p], s1 = col[p + 1], s2 = col[p + 2], s3 = col[p + 3];
        u16x8 v0 = *(const u16x8*)(h + (size_t)s0 * 256 + c0);
        u16x8 v1 = *(const u16x8*)(h + (size_t)s1 * 256 + c0);
        u16x8 v2 = *(const u16x8*)(h + (size_t)s2 * 256 + c0);
        u16x8 v3 = *(const u16x8*)(h + (size_t)s3 * 256 + c0);
#pragma unroll
        for (int j = 0; j < 8; j++) {
            a0[j] += bf2f(v0[j]);
            a1[j] += bf2f(v1[j]);
            a2[j] += bf2f(v2[j]);
            a3[j] += bf2f(v3[j]);
        }
    }
    for (; p < end; p++) {
        int s = col[p];
        u16x8 v = *(const u16x8*)(h + (size_t)s * 256 + c0);
#pragma unroll
        for (int j = 0; j < 8; j++) a0[j] += bf2f(v[j]);
    }
#pragma unroll
    for (int j = 0; j < 8; j++) a0[j] = (a0[j] + a1[j]) + (a2[j] + a3[j]);

    const float ndv = nd[w];
    const f32x4 bv0 = *(const f32x4*)(bias + c0);
    const f32x4 bv1 = *(const f32x4*)(bias + c0 + 4);
    const f32x4 al0 = *(const f32x4*)(alpha + c0);
    const f32x4 al1 = *(const f32x4*)(alpha + c0 + 4);
    float bb[8] = {bv0[0], bv0[1], bv0[2], bv0[3], bv1[0], bv1[1], bv1[2], bv1[3]};
    float aa[8] = {al0[0], al0[1], al0[2], al0[3], al1[0], al1[1], al1[2], al1[3]};
#pragma unroll
    for (int j = 0; j < 8; j++) {
        float s = a0[j] * ndv + bb[j];
        a0[j] = s > 0.f ? s : aa[j] * s;
    }

    if (obf) {
        const float nsv = ns[w];
        u16x8 o;
#pragma unroll
        for (int j = 0; j < 8; j++) o[j] = f2bf(a0[j] * nsv);
        *(u16x8*)(obf + (size_t)w * 256 + c0) = o;
    } else {
        f32x4 o0, o1;
        o0[0] = a0[0]; o0[1] = a0[1]; o0[2] = a0[2]; o0[3] = a0[3];
        o1[0] = a0[4]; o1[1] = a0[5]; o1[2] = a0[6]; o1[3] = a0[7];
        *(f32x4*)(of + (size_t)w * 256 + c0) = o0;
        *(f32x4*)(of + (size_t)w * 256 + c0 + 4) = o1;
    }
}

// ---------------- launch ----------------

extern "C" void kernel_launch(void* const* d_in, const int* in_sizes, int n_in,
                              void* d_out, int out_size, void* d_ws, size_t ws_size,
                              hipStream_t stream) {
    const float* feat = (const float*)d_in[0];
    const int* src = (const int*)d_in[1];
    const int* dst = (const int*)d_in[2];
    const float* W1 = (const float*)d_in[3];
    const float* b1 = (const float*)d_in[4];
    const float* a1 = (const float*)d_in[5];
    const float* W2 = (const float*)d_in[6];
    const float* b2 = (const float*)d_in[7];
    const float* a2 = (const float*)d_in[8];
    float* out = (float*)d_out;

    const int N = in_sizes[0] / 512;  // 100000
    const int E = in_sizes[1];        // 3200000
    const int NB = (N + (1 << BSHIFT) - 1) >> BSHIFT;  // 98

    char* ws = (char*)d_ws;
    size_t off = 0;
    auto take = [&](size_t bytes) {
        size_t o = off;
        off += (bytes + 255) & ~(size_t)255;
        return o;
    };
    int* deg_out = (int*)(ws + take((size_t)N * 4));
    int* deg_in = (int*)(ws + take((size_t)N * 4));
    float* nsrc = (float*)(ws + take((size_t)N * 4));
    float* ndst = (float*)(ws + take((size_t)N * 4));
    int* row_ptr = (int*)(ws + take((size_t)(N + 1) * 4));
    int* bcnt = (int*)(ws + take(1024));
    int* bcntA = bcnt, * bcntB = bcnt + 128;
    int* bbaseA = (int*)(ws + take(512));
    int* bbaseB = (int*)(ws + take(512));
    int* bcurA = (int*)(ws + take(512));
    int* bcurB = (int*)(ws + take(512));
    int* col = (int*)(ws + take((size_t)E * 4));
    u16* W1t = (u16*)(ws + take((size_t)512 * 256 * 2));
    u16* W2t = (u16*)(ws + take((size_t)256 * 256 * 2));
    u16* h = (u16*)(ws + take((size_t)N * 256 * 2));
    u16* x2 = (u16*)(ws + take((size_t)N * 256 * 2));
    int* kcode = (int*)h;  // alias: dead before gemm1 writes h (12.8MB <= 51.2MB)
    int* sb = (int*)x2;    // alias: dead before agg1 writes x2 (12.8MB <= 51.2MB)

    hipMemsetAsync(bcnt, 0, 1024, stream);

    const int chunk = 4096;
    bhist_k<<<(E + chunk - 1) / chunk, 256, 0, stream>>>(src, dst, bcntA, bcntB, E, chunk);
    bscan_k<<<1, 128, 0, stream>>>(bcntA, bcntB, bbaseA, bbaseB, bcurA, bcurB, row_ptr, NB, N, E);
    part_k<<<(E + chunk - 1) / chunk, 256, 0, stream>>>(src, dst, bcurA, bcurB, kcode, sb, E, chunk);
    bcsr_k<<<NB, 256, 0, stream>>>(kcode, bbaseA, row_ptr, deg_in, col, N);
    bdeg_k<<<NB, 256, 0, stream>>>(sb, bbaseB, deg_out, N);
    sortrow_k<<<(N * 64 + 255) / 256, 256, 0, stream>>>(row_ptr, col, N);
    norms_k<<<(N + 255) / 256, 256, 0, stream>>>(deg_out, deg_in, nsrc, ndst, N);

    convt_k<<<(512 * 256 + 255) / 256, 256, 0, stream>>>(W1, W1t, 512, 256);
    convt_k<<<(256 * 256 + 255) / 256, 256, 0, stream>>>(W2, W2t, 256, 256);

    dim3 gg((N + 127) / 128);
    int aggBlocks = (N * 32 + 255) / 256;

    // layer 1
    gemm_k<512, true><<<gg, 512, 0, stream>>>(feat, nsrc, W1t, h, N);
    agg_k<<<aggBlocks, 256, 0, stream>>>(h, row_ptr, col, ndst, b1, a1, nsrc, x2, nullptr, N);
    // layer 2
    gemm_k<256, false><<<gg, 512, 0, stream>>>(x2, nullptr, W2t, h, N);
    agg_k<<<aggBlocks, 256, 0, stream>>>(h, row_ptr, col, ndst, b2, a2, nullptr, nullptr, out, N);
}